// Round 1
// baseline (588.211 us; speedup 1.0000x reference)
//
#include <hip/hip_runtime.h>

#define NN 50000
#define NE 800000
#define D 128
#define H2D 64

constexpr int SCAN_CHUNK = 1024;

// ---------------- CSR build ----------------

__global__ void count_deg(const int* __restrict__ dst, int* __restrict__ deg, int n) {
    int i = blockIdx.x * blockDim.x + threadIdx.x;
    if (i < n) atomicAdd(&deg[dst[i]], 1);
}

__global__ void partial_sums(const int* __restrict__ deg, int* __restrict__ partials, int n) {
    __shared__ int sdata[256];
    int b = blockIdx.x, t = threadIdx.x;
    int base = b * SCAN_CHUNK;
    int sum = 0;
    for (int i = t; i < SCAN_CHUNK; i += 256) {
        int idx = base + i;
        if (idx < n) sum += deg[idx];
    }
    sdata[t] = sum;
    __syncthreads();
    for (int st = 128; st > 0; st >>= 1) {
        if (t < st) sdata[t] += sdata[t + st];
        __syncthreads();
    }
    if (t == 0) partials[b] = sdata[0];
}

__global__ void scan_partials(int* __restrict__ partials, int nb, int* __restrict__ total) {
    if (threadIdx.x == 0 && blockIdx.x == 0) {
        int run = 0;
        for (int i = 0; i < nb; ++i) { int v = partials[i]; partials[i] = run; run += v; }
        *total = run;
    }
}

__global__ void scan_chunks(const int* __restrict__ deg, const int* __restrict__ partials,
                            int* __restrict__ row_ptr, int* __restrict__ cursor,
                            float* __restrict__ inv_deg, int n) {
    __shared__ int soff[256];
    int b = blockIdx.x, t = threadIdx.x;
    int base = b * SCAN_CHUNK;
    int i0 = base + t * 4;
    int v[4];
    int s = 0;
#pragma unroll
    for (int j = 0; j < 4; ++j) {
        int idx = i0 + j;
        v[j] = (idx < n) ? deg[idx] : 0;
        s += v[j];
    }
    soff[t] = s;
    __syncthreads();
    for (int d = 1; d < 256; d <<= 1) {
        int val = (t >= d) ? soff[t - d] : 0;
        __syncthreads();
        soff[t] += val;
        __syncthreads();
    }
    int excl = soff[t] - s + partials[b];
#pragma unroll
    for (int j = 0; j < 4; ++j) {
        int idx = i0 + j;
        if (idx < n) {
            row_ptr[idx] = excl;
            cursor[idx] = excl;
            int dv = v[j] > 1 ? v[j] : 1;
            inv_deg[idx] = 1.0f / (float)dv;
            excl += v[j];
        }
    }
}

__global__ void fill_csr(const int* __restrict__ src, const int* __restrict__ dst,
                         int* __restrict__ cursor, int* __restrict__ csr, int n) {
    int i = blockIdx.x * blockDim.x + threadIdx.x;
    if (i < n) {
        int p = atomicAdd(&cursor[dst[i]], 1);
        csr[p] = src[i];
    }
}

// ---------------- mean aggregation (gather over CSR) ----------------
// one wave (64 lanes) per node, float2 per lane covers 128 dims
__global__ __launch_bounds__(256) void agg_mean(
    const float* __restrict__ X, const int* __restrict__ row_ptr,
    const int* __restrict__ csr, const float* __restrict__ inv_deg,
    float* __restrict__ out, int n_nodes) {
    int gtid = blockIdx.x * blockDim.x + threadIdx.x;
    int node = gtid >> 6;
    int lane = threadIdx.x & 63;
    if (node >= n_nodes) return;
    int beg = row_ptr[node], end = row_ptr[node + 1];
    const float2* X2 = (const float2*)X;
    float ax = 0.f, ay = 0.f;
    for (int e = beg; e < end; ++e) {
        int s = csr[e];
        float2 v = X2[(size_t)s * 64 + lane];
        ax += v.x;
        ay += v.y;
    }
    float w = inv_deg[node];
    float2 r;
    r.x = ax * w;
    r.y = ay * w;
    ((float2*)out)[(size_t)node * 64 + lane] = r;
}

// ---------------- fused dual GEMM: C = act(A1@W1 + A2@W2 + bias) ----------------
// A1,A2: [M,128] row-major. W1,W2: [128,BN]. C: [M,BN]. Virtual K = 256.
template <int BN, int TN>
__global__ __launch_bounds__(256) void gemm_dual(
    const float* __restrict__ A1, const float* __restrict__ A2,
    const float* __restrict__ W1, const float* __restrict__ W2,
    const float* __restrict__ bias, float* __restrict__ C, int M, int do_relu) {
    constexpr int BM = 128, BK = 16, TM = 8;
    constexpr int LDA = BM + 4;
    constexpr int LDB = BN + 4;
    __shared__ float As[BK][LDA];
    __shared__ float Bs[BK][LDB];
    const int tid = threadIdx.x;
    const int tm = tid >> 4;  // 0..15 -> row group (broadcast within 16-thread span)
    const int tn = tid & 15;  // 0..15 -> col group (coalesced stores)
    const int m0 = blockIdx.x * BM;

    float acc[TM][TN] = {};

    for (int kt = 0; kt < 16; ++kt) {
        const float* Asrc = (kt < 8) ? A1 : A2;
        const float* Wsrc = (kt < 8) ? W1 : W2;
        const int kbase = (kt * BK) & 127;

        // A tile: 128 rows x 16 cols, float4 loads, transposed store into LDS
        const float4* A4 = (const float4*)Asrc;
#pragma unroll
        for (int i = 0; i < 2; ++i) {
            int flat = tid + 256 * i;   // 0..511
            int m = flat >> 2;          // 0..127
            int k4 = (flat & 3) << 2;   // 0,4,8,12
            int gm = m0 + m;
            float4 v = make_float4(0.f, 0.f, 0.f, 0.f);
            if (gm < M) v = A4[(size_t)gm * (D / 4) + ((kbase + k4) >> 2)];
            As[k4 + 0][m] = v.x;
            As[k4 + 1][m] = v.y;
            As[k4 + 2][m] = v.z;
            As[k4 + 3][m] = v.w;
        }
        // B tile: 16 rows x BN cols, fully coalesced float4
        const float4* W4 = (const float4*)Wsrc;
#pragma unroll
        for (int i = 0; i < (BK * BN / 4) / 256; ++i) {
            int flat = tid + 256 * i;
            int n4 = flat % (BN / 4);
            int k = flat / (BN / 4);
            float4 v = W4[(size_t)(kbase + k) * (BN / 4) + n4];
            *(float4*)&Bs[k][n4 * 4] = v;
        }
        __syncthreads();

#pragma unroll
        for (int kk = 0; kk < BK; ++kk) {
            float a[TM], b[TN];
            *(float4*)&a[0] = *(const float4*)&As[kk][tm * TM];
            *(float4*)&a[4] = *(const float4*)&As[kk][tm * TM + 4];
#pragma unroll
            for (int j = 0; j < TN; j += 4)
                *(float4*)&b[j] = *(const float4*)&Bs[kk][tn * TN + j];
#pragma unroll
            for (int r = 0; r < TM; ++r)
#pragma unroll
                for (int c = 0; c < TN; ++c) acc[r][c] += a[r] * b[c];
        }
        __syncthreads();
    }

#pragma unroll
    for (int r = 0; r < TM; ++r) {
        int gm = m0 + tm * TM + r;
        if (gm >= M) continue;
#pragma unroll
        for (int c = 0; c < TN; c += 4) {
            int n = tn * TN + c;
            float4 v;
            v.x = acc[r][c + 0] + bias[n + 0];
            v.y = acc[r][c + 1] + bias[n + 1];
            v.z = acc[r][c + 2] + bias[n + 2];
            v.w = acc[r][c + 3] + bias[n + 3];
            if (do_relu) {
                v.x = fmaxf(v.x, 0.f);
                v.y = fmaxf(v.y, 0.f);
                v.z = fmaxf(v.z, 0.f);
                v.w = fmaxf(v.w, 0.f);
            }
            *(float4*)&C[(size_t)gm * BN + n] = v;
        }
    }
}

// ---------------- final linear: out[M,4] = H[M,64] @ Wo[64,4] + bo ----------------
__global__ __launch_bounds__(256) void final_linear(
    const float* __restrict__ H, const float* __restrict__ Wo,
    const float* __restrict__ bo, float* __restrict__ out, int M) {
    int n = blockIdx.x * blockDim.x + threadIdx.x;
    if (n >= M) return;
    float4 acc = *(const float4*)bo;
    const float4* W4 = (const float4*)Wo;
#pragma unroll 8
    for (int k = 0; k < 64; ++k) {
        float h = H[(size_t)n * 64 + k];
        float4 w = W4[k];
        acc.x += h * w.x;
        acc.y += h * w.y;
        acc.z += h * w.z;
        acc.w += h * w.w;
    }
    ((float4*)out)[n] = acc;
}

extern "C" void kernel_launch(void* const* d_in, const int* in_sizes, int n_in,
                              void* d_out, int out_size, void* d_ws, size_t ws_size,
                              hipStream_t stream) {
    const float* x = (const float*)d_in[0];
    const int* ei = (const int*)d_in[1];
    // d_in[2] = edge_type (unused by reference)
    const float* wl0 = (const float*)d_in[3];
    const float* wr0 = (const float*)d_in[4];
    const float* b0 = (const float*)d_in[5];
    const float* wl1 = (const float*)d_in[6];
    const float* wr1 = (const float*)d_in[7];
    const float* b1 = (const float*)d_in[8];
    const float* wl2 = (const float*)d_in[9];
    const float* wr2 = (const float*)d_in[10];
    const float* b2 = (const float*)d_in[11];
    const float* wo = (const float*)d_in[12];
    const float* bo = (const float*)d_in[13];

    const int n_nodes = in_sizes[0] / D;   // 50000
    const int n_edges = in_sizes[1] / 2;   // 800000
    const int* srcp = ei;
    const int* dstp = ei + n_edges;

    // workspace carve-up (256B aligned slices)
    char* ws = (char*)d_ws;
    size_t off = 0;
    auto carve = [&](size_t bytes) -> void* {
        void* p = ws + off;
        off = (off + bytes + 255) & ~(size_t)255;
        return p;
    };
    int* deg = (int*)carve((size_t)n_nodes * 4);
    int* row_ptr = (int*)carve((size_t)(n_nodes + 1) * 4);
    int* cursor = (int*)carve((size_t)n_nodes * 4);
    int* partials = (int*)carve(256 * 4);
    float* inv_deg = (float*)carve((size_t)n_nodes * 4);
    int* csr = (int*)carve((size_t)n_edges * 4);
    float* agg = (float*)carve((size_t)n_nodes * D * 4);
    float* bufA = (float*)carve((size_t)n_nodes * D * 4);
    float* bufB = (float*)carve((size_t)n_nodes * D * 4);

    const int nchunk = (n_nodes + SCAN_CHUNK - 1) / SCAN_CHUNK;  // 49

    hipMemsetAsync(deg, 0, (size_t)n_nodes * 4, stream);
    count_deg<<<(n_edges + 255) / 256, 256, 0, stream>>>(dstp, deg, n_edges);
    partial_sums<<<nchunk, 256, 0, stream>>>(deg, partials, n_nodes);
    scan_partials<<<1, 64, 0, stream>>>(partials, nchunk, row_ptr + n_nodes);
    scan_chunks<<<nchunk, 256, 0, stream>>>(deg, partials, row_ptr, cursor, inv_deg, n_nodes);
    fill_csr<<<(n_edges + 255) / 256, 256, 0, stream>>>(srcp, dstp, cursor, csr, n_edges);

    const int agg_blocks = (n_nodes * 64 + 255) / 256;  // one wave per node
    const int gemm_blocks = (n_nodes + 127) / 128;

    // layer 0
    agg_mean<<<agg_blocks, 256, 0, stream>>>(x, row_ptr, csr, inv_deg, agg, n_nodes);
    gemm_dual<128, 8><<<gemm_blocks, 256, 0, stream>>>(agg, x, wl0, wr0, b0, bufA, n_nodes, 1);
    // layer 1
    agg_mean<<<agg_blocks, 256, 0, stream>>>(bufA, row_ptr, csr, inv_deg, agg, n_nodes);
    gemm_dual<128, 8><<<gemm_blocks, 256, 0, stream>>>(agg, bufA, wl1, wr1, b1, bufB, n_nodes, 1);
    // layer 2 (out dim 64)
    agg_mean<<<agg_blocks, 256, 0, stream>>>(bufB, row_ptr, csr, inv_deg, agg, n_nodes);
    gemm_dual<64, 4><<<gemm_blocks, 256, 0, stream>>>(agg, bufB, wl2, wr2, b2, bufA, n_nodes, 1);
    // output head
    final_linear<<<(n_nodes + 255) / 256, 256, 0, stream>>>(bufA, wo, bo, (float*)d_out, n_nodes);
}

// Round 2
// 493.220 us; speedup vs baseline: 1.1926x; 1.1926x over previous
//
#include <hip/hip_runtime.h>

#define D 128

constexpr int SCAN_CHUNK = 1024;

// ---------------- CSR build ----------------

__global__ void count_deg(const int* __restrict__ dst, int* __restrict__ deg, int n) {
    int i = blockIdx.x * blockDim.x + threadIdx.x;
    if (i < n) atomicAdd(&deg[dst[i]], 1);
}

__global__ void partial_sums(const int* __restrict__ deg, int* __restrict__ partials, int n) {
    __shared__ int sdata[256];
    int b = blockIdx.x, t = threadIdx.x;
    int base = b * SCAN_CHUNK;
    int sum = 0;
    for (int i = t; i < SCAN_CHUNK; i += 256) {
        int idx = base + i;
        if (idx < n) sum += deg[idx];
    }
    sdata[t] = sum;
    __syncthreads();
    for (int st = 128; st > 0; st >>= 1) {
        if (t < st) sdata[t] += sdata[t + st];
        __syncthreads();
    }
    if (t == 0) partials[b] = sdata[0];
}

__global__ void scan_partials(int* __restrict__ partials, int nb, int* __restrict__ total) {
    if (threadIdx.x == 0 && blockIdx.x == 0) {
        int run = 0;
        for (int i = 0; i < nb; ++i) { int v = partials[i]; partials[i] = run; run += v; }
        *total = run;
    }
}

__global__ void scan_chunks(const int* __restrict__ deg, const int* __restrict__ partials,
                            int* __restrict__ row_ptr, int* __restrict__ cursor,
                            float* __restrict__ inv_deg, int n) {
    __shared__ int soff[256];
    int b = blockIdx.x, t = threadIdx.x;
    int base = b * SCAN_CHUNK;
    int i0 = base + t * 4;
    int v[4];
    int s = 0;
#pragma unroll
    for (int j = 0; j < 4; ++j) {
        int idx = i0 + j;
        v[j] = (idx < n) ? deg[idx] : 0;
        s += v[j];
    }
    soff[t] = s;
    __syncthreads();
    for (int d = 1; d < 256; d <<= 1) {
        int val = (t >= d) ? soff[t - d] : 0;
        __syncthreads();
        soff[t] += val;
        __syncthreads();
    }
    int excl = soff[t] - s + partials[b];
#pragma unroll
    for (int j = 0; j < 4; ++j) {
        int idx = i0 + j;
        if (idx < n) {
            row_ptr[idx] = excl;
            cursor[idx] = excl;
            int dv = v[j] > 1 ? v[j] : 1;
            inv_deg[idx] = 1.0f / (float)dv;
            excl += v[j];
        }
    }
}

__global__ void fill_csr(const int* __restrict__ src, const int* __restrict__ dst,
                         int* __restrict__ cursor, int* __restrict__ csr, int n) {
    int i = blockIdx.x * blockDim.x + threadIdx.x;
    if (i < n) {
        int p = atomicAdd(&cursor[dst[i]], 1);
        csr[p] = src[i];
    }
}

// ---------------- GEMM pair: P = A@W1, Q = A@W2 + bias ----------------
// A: [M,128] row-major, W1/W2: [128,BN], P/Q: [M,BN]. blockIdx.y selects P/Q.
template <int BN, int TN>
__global__ __launch_bounds__(256) void gemm_pair(
    const float* __restrict__ A, const float* __restrict__ W1,
    const float* __restrict__ W2, const float* __restrict__ bias,
    float* __restrict__ P, float* __restrict__ Q, int M) {
    constexpr int BM = 128, BK = 16, TM = 8;
    constexpr int LDA = BM + 4;
    constexpr int LDB = BN + 4;
    __shared__ float As[BK][LDA];
    __shared__ float Bs[BK][LDB];
    const int tid = threadIdx.x;
    const int tm = tid >> 4;
    const int tn = tid & 15;
    const int m0 = blockIdx.x * BM;
    const int isQ = blockIdx.y;
    const float* W = isQ ? W2 : W1;
    float* C = isQ ? Q : P;

    float acc[TM][TN] = {};

    for (int kt = 0; kt < 8; ++kt) {
        const int kbase = kt * BK;
        // A tile: 128 rows x 16 cols, float4 loads, transposed into LDS
        const float4* A4 = (const float4*)A;
#pragma unroll
        for (int i = 0; i < 2; ++i) {
            int flat = tid + 256 * i;   // 0..511
            int m = flat >> 2;          // 0..127
            int k4 = (flat & 3) << 2;   // 0,4,8,12
            int gm = m0 + m;
            float4 v = make_float4(0.f, 0.f, 0.f, 0.f);
            if (gm < M) v = A4[(size_t)gm * (D / 4) + ((kbase + k4) >> 2)];
            As[k4 + 0][m] = v.x;
            As[k4 + 1][m] = v.y;
            As[k4 + 2][m] = v.z;
            As[k4 + 3][m] = v.w;
        }
        // B tile: 16 rows x BN cols
        const float4* W4 = (const float4*)W;
#pragma unroll
        for (int i = 0; i < (BK * BN / 4) / 256; ++i) {
            int flat = tid + 256 * i;
            int n4 = flat % (BN / 4);
            int k = flat / (BN / 4);
            float4 v = W4[(size_t)(kbase + k) * (BN / 4) + n4];
            *(float4*)&Bs[k][n4 * 4] = v;
        }
        __syncthreads();

#pragma unroll
        for (int kk = 0; kk < BK; ++kk) {
            float a[TM], b[TN];
            *(float4*)&a[0] = *(const float4*)&As[kk][tm * TM];
            *(float4*)&a[4] = *(const float4*)&As[kk][tm * TM + 4];
#pragma unroll
            for (int j = 0; j < TN; j += 4)
                *(float4*)&b[j] = *(const float4*)&Bs[kk][tn * TN + j];
#pragma unroll
            for (int r = 0; r < TM; ++r)
#pragma unroll
                for (int c = 0; c < TN; ++c) acc[r][c] += a[r] * b[c];
        }
        __syncthreads();
    }

#pragma unroll
    for (int r = 0; r < TM; ++r) {
        int gm = m0 + tm * TM + r;
        if (gm >= M) continue;
#pragma unroll
        for (int c = 0; c < TN; c += 4) {
            int n = tn * TN + c;
            float4 v;
            v.x = acc[r][c + 0];
            v.y = acc[r][c + 1];
            v.z = acc[r][c + 2];
            v.w = acc[r][c + 3];
            if (isQ) {
                v.x += bias[n + 0];
                v.y += bias[n + 1];
                v.z += bias[n + 2];
                v.w += bias[n + 3];
            }
            *(float4*)&C[(size_t)gm * BN + n] = v;
        }
    }
}

// ---------------- fused aggregation, 128-dim: out = relu(mean_gather(P) + Q) ----------------
// one wave per node, float2 per lane; edge loop unrolled x4 for 4 outstanding gathers
__global__ __launch_bounds__(256) void agg_fused128(
    const float* __restrict__ P, const float* __restrict__ Q,
    const int* __restrict__ row_ptr, const int* __restrict__ csr,
    const float* __restrict__ inv_deg, float* __restrict__ out, int n_nodes) {
    int node = (blockIdx.x * blockDim.x + threadIdx.x) >> 6;
    int lane = threadIdx.x & 63;
    if (node >= n_nodes) return;
    int beg = row_ptr[node], end = row_ptr[node + 1];
    const float2* P2 = (const float2*)P;
    float ax0 = 0, ay0 = 0, ax1 = 0, ay1 = 0, ax2 = 0, ay2 = 0, ax3 = 0, ay3 = 0;
    int e = beg;
    for (; e + 4 <= end; e += 4) {
        int s0 = csr[e + 0], s1 = csr[e + 1], s2 = csr[e + 2], s3 = csr[e + 3];
        float2 v0 = P2[(size_t)s0 * 64 + lane];
        float2 v1 = P2[(size_t)s1 * 64 + lane];
        float2 v2 = P2[(size_t)s2 * 64 + lane];
        float2 v3 = P2[(size_t)s3 * 64 + lane];
        ax0 += v0.x; ay0 += v0.y;
        ax1 += v1.x; ay1 += v1.y;
        ax2 += v2.x; ay2 += v2.y;
        ax3 += v3.x; ay3 += v3.y;
    }
    for (; e < end; ++e) {
        int s = csr[e];
        float2 v = P2[(size_t)s * 64 + lane];
        ax0 += v.x; ay0 += v.y;
    }
    float w = inv_deg[node];
    float sx = (ax0 + ax1) + (ax2 + ax3);
    float sy = (ay0 + ay1) + (ay2 + ay3);
    float2 q = ((const float2*)Q)[(size_t)node * 64 + lane];
    float2 r;
    r.x = fmaxf(fmaf(sx, w, q.x), 0.f);
    r.y = fmaxf(fmaf(sy, w, q.y), 0.f);
    ((float2*)out)[(size_t)node * 64 + lane] = r;
}

// ---------------- fused aggregation 64-dim + output head ----------------
// h3 = relu(mean_gather(P) + Q) computed per-lane (lane = dim), then
// out[node, 0..3] = h3 @ Wo + bo via wave shuffle reduction.
__global__ __launch_bounds__(256) void agg64_head(
    const float* __restrict__ P, const float* __restrict__ Q,
    const int* __restrict__ row_ptr, const int* __restrict__ csr,
    const float* __restrict__ inv_deg, const float* __restrict__ Wo,
    const float* __restrict__ bo, float* __restrict__ out, int n_nodes) {
    int node = (blockIdx.x * blockDim.x + threadIdx.x) >> 6;
    int lane = threadIdx.x & 63;
    if (node >= n_nodes) return;
    int beg = row_ptr[node], end = row_ptr[node + 1];
    float a0 = 0, a1 = 0, a2 = 0, a3 = 0;
    int e = beg;
    for (; e + 4 <= end; e += 4) {
        int s0 = csr[e + 0], s1 = csr[e + 1], s2 = csr[e + 2], s3 = csr[e + 3];
        a0 += P[(size_t)s0 * 64 + lane];
        a1 += P[(size_t)s1 * 64 + lane];
        a2 += P[(size_t)s2 * 64 + lane];
        a3 += P[(size_t)s3 * 64 + lane];
    }
    for (; e < end; ++e) a0 += P[(size_t)csr[e] * 64 + lane];
    float w = inv_deg[node];
    float h = fmaxf(fmaf((a0 + a1) + (a2 + a3), w, Q[(size_t)node * 64 + lane]), 0.f);
    // head: each lane contributes h * Wo[lane][c], reduce across 64 lanes
    float4 wv = ((const float4*)Wo)[lane];
    float c0 = h * wv.x, c1 = h * wv.y, c2 = h * wv.z, c3 = h * wv.w;
#pragma unroll
    for (int m = 32; m > 0; m >>= 1) {
        c0 += __shfl_xor(c0, m);
        c1 += __shfl_xor(c1, m);
        c2 += __shfl_xor(c2, m);
        c3 += __shfl_xor(c3, m);
    }
    if (lane == 0) {
        float4 r;
        r.x = c0 + bo[0];
        r.y = c1 + bo[1];
        r.z = c2 + bo[2];
        r.w = c3 + bo[3];
        ((float4*)out)[node] = r;
    }
}

extern "C" void kernel_launch(void* const* d_in, const int* in_sizes, int n_in,
                              void* d_out, int out_size, void* d_ws, size_t ws_size,
                              hipStream_t stream) {
    const float* x = (const float*)d_in[0];
    const int* ei = (const int*)d_in[1];
    const float* wl0 = (const float*)d_in[3];
    const float* wr0 = (const float*)d_in[4];
    const float* b0 = (const float*)d_in[5];
    const float* wl1 = (const float*)d_in[6];
    const float* wr1 = (const float*)d_in[7];
    const float* b1 = (const float*)d_in[8];
    const float* wl2 = (const float*)d_in[9];
    const float* wr2 = (const float*)d_in[10];
    const float* b2 = (const float*)d_in[11];
    const float* wo = (const float*)d_in[12];
    const float* bo = (const float*)d_in[13];

    const int n_nodes = in_sizes[0] / D;   // 50000
    const int n_edges = in_sizes[1] / 2;   // 800000
    const int* srcp = ei;
    const int* dstp = ei + n_edges;

    char* ws = (char*)d_ws;
    size_t off = 0;
    auto carve = [&](size_t bytes) -> void* {
        void* p = ws + off;
        off = (off + bytes + 255) & ~(size_t)255;
        return p;
    };
    int* deg = (int*)carve((size_t)n_nodes * 4);
    int* row_ptr = (int*)carve((size_t)(n_nodes + 1) * 4);
    int* cursor = (int*)carve((size_t)n_nodes * 4);
    int* partials = (int*)carve(256 * 4);
    float* inv_deg = (float*)carve((size_t)n_nodes * 4);
    int* csr = (int*)carve((size_t)n_edges * 4);
    float* Pbuf = (float*)carve((size_t)n_nodes * D * 4);
    float* Qbuf = (float*)carve((size_t)n_nodes * D * 4);
    float* hA = (float*)carve((size_t)n_nodes * D * 4);
    float* hB = (float*)carve((size_t)n_nodes * D * 4);

    const int nchunk = (n_nodes + SCAN_CHUNK - 1) / SCAN_CHUNK;

    hipMemsetAsync(deg, 0, (size_t)n_nodes * 4, stream);
    count_deg<<<(n_edges + 255) / 256, 256, 0, stream>>>(dstp, deg, n_edges);
    partial_sums<<<nchunk, 256, 0, stream>>>(deg, partials, n_nodes);
    scan_partials<<<1, 64, 0, stream>>>(partials, nchunk, row_ptr + n_nodes);
    scan_chunks<<<nchunk, 256, 0, stream>>>(deg, partials, row_ptr, cursor, inv_deg, n_nodes);
    fill_csr<<<(n_edges + 255) / 256, 256, 0, stream>>>(srcp, dstp, cursor, csr, n_edges);

    const int agg_blocks = (n_nodes * 64 + 255) / 256;
    const dim3 gemm_grid((n_nodes + 127) / 128, 2);

    // layer 0: P = x@wl0, Q = x@wr0 + b0; h = relu(agg(P) + Q)
    gemm_pair<128, 8><<<gemm_grid, 256, 0, stream>>>(x, wl0, wr0, b0, Pbuf, Qbuf, n_nodes);
    agg_fused128<<<agg_blocks, 256, 0, stream>>>(Pbuf, Qbuf, row_ptr, csr, inv_deg, hA, n_nodes);
    // layer 1
    gemm_pair<128, 8><<<gemm_grid, 256, 0, stream>>>(hA, wl1, wr1, b1, Pbuf, Qbuf, n_nodes);
    agg_fused128<<<agg_blocks, 256, 0, stream>>>(Pbuf, Qbuf, row_ptr, csr, inv_deg, hB, n_nodes);
    // layer 2 (64-dim) + head, fused
    gemm_pair<64, 4><<<gemm_grid, 256, 0, stream>>>(hB, wl2, wr2, b2, Pbuf, Qbuf, n_nodes);
    agg64_head<<<agg_blocks, 256, 0, stream>>>(Pbuf, Qbuf, row_ptr, csr, inv_deg,
                                               wo, bo, (float*)d_out, n_nodes);
}

// Round 3
// 469.805 us; speedup vs baseline: 1.2520x; 1.0498x over previous
//
#include <hip/hip_runtime.h>

#define D 128

constexpr int SCAN_CHUNK = 1024;

using short8 = __attribute__((ext_vector_type(8))) short;
using f32x4 = __attribute__((ext_vector_type(4))) float;

// split fp32 into hi/lo bf16 (truncation; residual exact in fp32)
__device__ inline void splitf(float v, unsigned short& h, unsigned short& l) {
    unsigned b = __float_as_uint(v);
    h = (unsigned short)(b >> 16);
    float fh = __uint_as_float(b & 0xffff0000u);
    float r = v - fh;
    l = (unsigned short)(__float_as_uint(r) >> 16);
}

// ---------------- CSR build ----------------

__global__ void count_deg(const int* __restrict__ dst, int* __restrict__ deg, int n) {
    int i = blockIdx.x * blockDim.x + threadIdx.x;
    if (i < n) atomicAdd(&deg[dst[i]], 1);
}

__global__ void partial_sums(const int* __restrict__ deg, int* __restrict__ partials, int n) {
    __shared__ int sdata[256];
    int b = blockIdx.x, t = threadIdx.x;
    int base = b * SCAN_CHUNK;
    int sum = 0;
    for (int i = t; i < SCAN_CHUNK; i += 256) {
        int idx = base + i;
        if (idx < n) sum += deg[idx];
    }
    sdata[t] = sum;
    __syncthreads();
    for (int st = 128; st > 0; st >>= 1) {
        if (t < st) sdata[t] += sdata[t + st];
        __syncthreads();
    }
    if (t == 0) partials[b] = sdata[0];
}

__global__ void scan_partials(int* __restrict__ partials, int nb, int* __restrict__ total) {
    if (threadIdx.x == 0 && blockIdx.x == 0) {
        int run = 0;
        for (int i = 0; i < nb; ++i) { int v = partials[i]; partials[i] = run; run += v; }
        *total = run;
    }
}

__global__ void scan_chunks(const int* __restrict__ deg, const int* __restrict__ partials,
                            int* __restrict__ row_ptr, int* __restrict__ cursor,
                            float* __restrict__ inv_deg, int n) {
    __shared__ int soff[256];
    int b = blockIdx.x, t = threadIdx.x;
    int base = b * SCAN_CHUNK;
    int i0 = base + t * 4;
    int v[4];
    int s = 0;
#pragma unroll
    for (int j = 0; j < 4; ++j) {
        int idx = i0 + j;
        v[j] = (idx < n) ? deg[idx] : 0;
        s += v[j];
    }
    soff[t] = s;
    __syncthreads();
    for (int d = 1; d < 256; d <<= 1) {
        int val = (t >= d) ? soff[t - d] : 0;
        __syncthreads();
        soff[t] += val;
        __syncthreads();
    }
    int excl = soff[t] - s + partials[b];
#pragma unroll
    for (int j = 0; j < 4; ++j) {
        int idx = i0 + j;
        if (idx < n) {
            row_ptr[idx] = excl;
            cursor[idx] = excl;
            int dv = v[j] > 1 ? v[j] : 1;
            inv_deg[idx] = 1.0f / (float)dv;
            excl += v[j];
        }
    }
}

__global__ void fill_csr(const int* __restrict__ src, const int* __restrict__ dst,
                         int* __restrict__ cursor, int* __restrict__ csr, int n) {
    int i = blockIdx.x * blockDim.x + threadIdx.x;
    if (i < n) {
        int p = atomicAdd(&cursor[dst[i]], 1);
        csr[p] = src[i];
    }
}

// ---------------- input split: x -> xh, xl (bf16 hi/lo) ----------------
__global__ __launch_bounds__(256) void split_x(const float4* __restrict__ x,
                                               ushort4* __restrict__ xh,
                                               ushort4* __restrict__ xl, int n4) {
    int i = blockIdx.x * blockDim.x + threadIdx.x;
    if (i >= n4) return;
    float4 v = x[i];
    ushort4 h, l;
    splitf(v.x, h.x, l.x);
    splitf(v.y, h.y, l.y);
    splitf(v.z, h.z, l.z);
    splitf(v.w, h.w, l.w);
    xh[i] = h;
    xl[i] = l;
}

// ---------------- weight split+transpose: W[K=128][N] -> Wt_hi/lo [N][128] ----------------
struct WSplitArgs {
    const float* src[6];
    unsigned short* dh[6];
    unsigned short* dl[6];
    int n[6];  // N per matrix (128 or 64)
};

__global__ __launch_bounds__(256) void split_w(WSplitArgs a) {
    int m = blockIdx.y;
    int N = a.n[m];
    int e = blockIdx.x * 256 + threadIdx.x;
    if (e >= 128 * N) return;
    int sh = (N == 128) ? 7 : 6;
    int k = e >> sh;
    int n = e & (N - 1);
    float v = a.src[m][e];
    unsigned short h, l;
    splitf(v, h, l);
    a.dh[m][n * 128 + k] = h;
    a.dl[m][n * 128 + k] = l;
}

// ---------------- MFMA GEMM: C = A@W (+bias), split-bf16, no LDS ----------------
// A: hi/lo bf16 [M][128]. Wt: hi/lo bf16 [BN][128] (transposed). C: fp32 [M][BN].
// block = 4 waves; wave w covers n-tiles [w*NT, w*NT+NT); block covers 128 rows.
// blockIdx.y: 0 -> W1 into P (no bias), 1 -> W2 into Q (+bias).
template <int BN, int NT>
__global__ __launch_bounds__(256) void gemm_mfma(
    const unsigned short* __restrict__ Ah, const unsigned short* __restrict__ Al,
    const unsigned short* __restrict__ W1h, const unsigned short* __restrict__ W1l,
    const unsigned short* __restrict__ W2h, const unsigned short* __restrict__ W2l,
    const float* __restrict__ bias, float* __restrict__ P, float* __restrict__ Q, int M) {
    const int tid = threadIdx.x;
    const int wave = tid >> 6;
    const int lane = tid & 63;
    const int l15 = lane & 15;
    const int q = lane >> 4;
    const int isQ = blockIdx.y;
    const unsigned short* Wh = isQ ? W2h : W1h;
    const unsigned short* Wl = isQ ? W2l : W1l;
    float* C = isQ ? Q : P;

    // preload all B fragments into registers (weights stay resident)
    short8 Bh[NT][4], Bl[NT][4];
    float bvs[NT];
#pragma unroll
    for (int nt = 0; nt < NT; ++nt) {
        int n = (wave * NT + nt) * 16 + l15;
#pragma unroll
        for (int kt = 0; kt < 4; ++kt) {
            int off = n * 128 + kt * 32 + q * 8;
            Bh[nt][kt] = *(const short8*)(Wh + off);
            Bl[nt][kt] = *(const short8*)(Wl + off);
        }
        bvs[nt] = isQ ? bias[n] : 0.f;
    }

    const int m0 = blockIdx.x * 128;
    for (int mt = 0; mt < 8; ++mt) {
        int row = m0 + mt * 16 + l15;
        int rc = row < M ? row : M - 1;
        const unsigned short* ap = Ah + (size_t)rc * 128 + q * 8;
        const unsigned short* alp = Al + (size_t)rc * 128 + q * 8;
        short8 Afh[4], Afl[4];
#pragma unroll
        for (int kt = 0; kt < 4; ++kt) {
            Afh[kt] = *(const short8*)(ap + kt * 32);
            Afl[kt] = *(const short8*)(alp + kt * 32);
        }
        f32x4 acc[NT];
#pragma unroll
        for (int nt = 0; nt < NT; ++nt) acc[nt] = (f32x4)(0.f);
#pragma unroll
        for (int kt = 0; kt < 4; ++kt) {
#pragma unroll
            for (int nt = 0; nt < NT; ++nt) {
                acc[nt] = __builtin_amdgcn_mfma_f32_16x16x32_bf16(Afh[kt], Bh[nt][kt], acc[nt], 0, 0, 0);
                acc[nt] = __builtin_amdgcn_mfma_f32_16x16x32_bf16(Afh[kt], Bl[nt][kt], acc[nt], 0, 0, 0);
                acc[nt] = __builtin_amdgcn_mfma_f32_16x16x32_bf16(Afl[kt], Bh[nt][kt], acc[nt], 0, 0, 0);
            }
        }
        int orow = m0 + mt * 16 + q * 4;
#pragma unroll
        for (int nt = 0; nt < NT; ++nt) {
            int col = (wave * NT + nt) * 16 + l15;
#pragma unroll
            for (int r = 0; r < 4; ++r) {
                int rr = orow + r;
                if (rr < M) C[(size_t)rr * BN + col] = acc[nt][r] + bvs[nt];
            }
        }
    }
}

// ---------------- fused aggregation 128-dim: h = relu(mean_gather(P) + Q) -> bf16 hi/lo ----------------
__global__ __launch_bounds__(256) void agg_fused128(
    const float* __restrict__ P, const float* __restrict__ Q,
    const int* __restrict__ row_ptr, const int* __restrict__ csr,
    const float* __restrict__ inv_deg, unsigned short* __restrict__ Hh,
    unsigned short* __restrict__ Hl, int n_nodes) {
    int node = (blockIdx.x * blockDim.x + threadIdx.x) >> 6;
    int lane = threadIdx.x & 63;
    if (node >= n_nodes) return;
    int beg = row_ptr[node], end = row_ptr[node + 1];
    const float2* P2 = (const float2*)P;
    float ax[8] = {}, ay[8] = {};
    int e = beg;
    for (; e + 8 <= end; e += 8) {
#pragma unroll
        for (int j = 0; j < 8; ++j) {
            int s = csr[e + j];
            float2 v = P2[(size_t)s * 64 + lane];
            ax[j] += v.x;
            ay[j] += v.y;
        }
    }
    for (; e < end; ++e) {
        int s = csr[e];
        float2 v = P2[(size_t)s * 64 + lane];
        ax[0] += v.x;
        ay[0] += v.y;
    }
    float w = inv_deg[node];
    float sx = ((ax[0] + ax[1]) + (ax[2] + ax[3])) + ((ax[4] + ax[5]) + (ax[6] + ax[7]));
    float sy = ((ay[0] + ay[1]) + (ay[2] + ay[3])) + ((ay[4] + ay[5]) + (ay[6] + ay[7]));
    float2 qv = ((const float2*)Q)[(size_t)node * 64 + lane];
    float hx = fmaxf(fmaf(sx, w, qv.x), 0.f);
    float hy = fmaxf(fmaf(sy, w, qv.y), 0.f);
    ushort2 hv, lv;
    splitf(hx, hv.x, lv.x);
    splitf(hy, hv.y, lv.y);
    ((ushort2*)Hh)[(size_t)node * 64 + lane] = hv;
    ((ushort2*)Hl)[(size_t)node * 64 + lane] = lv;
}

// ---------------- fused aggregation 64-dim + output head ----------------
__global__ __launch_bounds__(256) void agg64_head(
    const float* __restrict__ P, const float* __restrict__ Q,
    const int* __restrict__ row_ptr, const int* __restrict__ csr,
    const float* __restrict__ inv_deg, const float* __restrict__ Wo,
    const float* __restrict__ bo, float* __restrict__ out, int n_nodes) {
    int node = (blockIdx.x * blockDim.x + threadIdx.x) >> 6;
    int lane = threadIdx.x & 63;
    if (node >= n_nodes) return;
    int beg = row_ptr[node], end = row_ptr[node + 1];
    float a[8] = {};
    int e = beg;
    for (; e + 8 <= end; e += 8) {
#pragma unroll
        for (int j = 0; j < 8; ++j) a[j] += P[(size_t)csr[e + j] * 64 + lane];
    }
    for (; e < end; ++e) a[0] += P[(size_t)csr[e] * 64 + lane];
    float w = inv_deg[node];
    float s = ((a[0] + a[1]) + (a[2] + a[3])) + ((a[4] + a[5]) + (a[6] + a[7]));
    float h = fmaxf(fmaf(s, w, Q[(size_t)node * 64 + lane]), 0.f);
    float4 wv = ((const float4*)Wo)[lane];
    float c0 = h * wv.x, c1 = h * wv.y, c2 = h * wv.z, c3 = h * wv.w;
#pragma unroll
    for (int m = 32; m > 0; m >>= 1) {
        c0 += __shfl_xor(c0, m);
        c1 += __shfl_xor(c1, m);
        c2 += __shfl_xor(c2, m);
        c3 += __shfl_xor(c3, m);
    }
    if (lane == 0) {
        float4 r;
        r.x = c0 + bo[0];
        r.y = c1 + bo[1];
        r.z = c2 + bo[2];
        r.w = c3 + bo[3];
        ((float4*)out)[node] = r;
    }
}

extern "C" void kernel_launch(void* const* d_in, const int* in_sizes, int n_in,
                              void* d_out, int out_size, void* d_ws, size_t ws_size,
                              hipStream_t stream) {
    const float* x = (const float*)d_in[0];
    const int* ei = (const int*)d_in[1];
    const float* wl0 = (const float*)d_in[3];
    const float* wr0 = (const float*)d_in[4];
    const float* b0 = (const float*)d_in[5];
    const float* wl1 = (const float*)d_in[6];
    const float* wr1 = (const float*)d_in[7];
    const float* b1 = (const float*)d_in[8];
    const float* wl2 = (const float*)d_in[9];
    const float* wr2 = (const float*)d_in[10];
    const float* b2 = (const float*)d_in[11];
    const float* wo = (const float*)d_in[12];
    const float* bo = (const float*)d_in[13];

    const int n_nodes = in_sizes[0] / D;   // 50000
    const int n_edges = in_sizes[1] / 2;   // 800000
    const int* srcp = ei;
    const int* dstp = ei + n_edges;

    char* ws = (char*)d_ws;
    size_t off = 0;
    auto carve = [&](size_t bytes) -> void* {
        void* p = ws + off;
        off = (off + bytes + 255) & ~(size_t)255;
        return p;
    };
    int* deg = (int*)carve((size_t)n_nodes * 4);
    int* row_ptr = (int*)carve((size_t)(n_nodes + 1) * 4);
    int* cursor = (int*)carve((size_t)n_nodes * 4);
    int* partials = (int*)carve(256 * 4);
    float* inv_deg = (float*)carve((size_t)n_nodes * 4);
    int* csr = (int*)carve((size_t)n_edges * 4);
    unsigned short* xh = (unsigned short*)carve((size_t)n_nodes * D * 2);
    unsigned short* xl = (unsigned short*)carve((size_t)n_nodes * D * 2);
    float* Pbuf = (float*)carve((size_t)n_nodes * D * 4);
    float* Qbuf = (float*)carve((size_t)n_nodes * D * 4);
    unsigned short* hh = (unsigned short*)carve((size_t)n_nodes * D * 2);
    unsigned short* hl = (unsigned short*)carve((size_t)n_nodes * D * 2);
    // split/transposed weights: 4x [128][128] + 2x [64][128], hi+lo each
    unsigned short* wt = (unsigned short*)carve((size_t)(4 * 128 * 128 + 2 * 64 * 128) * 2 * 2);
    unsigned short* wl0h = wt;
    unsigned short* wl0l = wl0h + 128 * 128;
    unsigned short* wr0h = wl0l + 128 * 128;
    unsigned short* wr0l = wr0h + 128 * 128;
    unsigned short* wl1h = wr0l + 128 * 128;
    unsigned short* wl1l = wl1h + 128 * 128;
    unsigned short* wr1h = wl1l + 128 * 128;
    unsigned short* wr1l = wr1h + 128 * 128;
    unsigned short* wl2h = wr1l + 128 * 128;
    unsigned short* wl2l = wl2h + 64 * 128;
    unsigned short* wr2h = wl2l + 64 * 128;
    unsigned short* wr2l = wr2h + 64 * 128;

    const int nchunk = (n_nodes + SCAN_CHUNK - 1) / SCAN_CHUNK;

    hipMemsetAsync(deg, 0, (size_t)n_nodes * 4, stream);
    count_deg<<<(n_edges + 255) / 256, 256, 0, stream>>>(dstp, deg, n_edges);
    partial_sums<<<nchunk, 256, 0, stream>>>(deg, partials, n_nodes);
    scan_partials<<<1, 64, 0, stream>>>(partials, nchunk, row_ptr + n_nodes);
    scan_chunks<<<nchunk, 256, 0, stream>>>(deg, partials, row_ptr, cursor, inv_deg, n_nodes);
    fill_csr<<<(n_edges + 255) / 256, 256, 0, stream>>>(srcp, dstp, cursor, csr, n_edges);

    WSplitArgs wa;
    wa.src[0] = wl0; wa.dh[0] = wl0h; wa.dl[0] = wl0l; wa.n[0] = 128;
    wa.src[1] = wr0; wa.dh[1] = wr0h; wa.dl[1] = wr0l; wa.n[1] = 128;
    wa.src[2] = wl1; wa.dh[2] = wl1h; wa.dl[2] = wl1l; wa.n[2] = 128;
    wa.src[3] = wr1; wa.dh[3] = wr1h; wa.dl[3] = wr1l; wa.n[3] = 128;
    wa.src[4] = wl2; wa.dh[4] = wl2h; wa.dl[4] = wl2l; wa.n[4] = 64;
    wa.src[5] = wr2; wa.dh[5] = wr2h; wa.dl[5] = wr2l; wa.n[5] = 64;
    split_w<<<dim3(64, 6), 256, 0, stream>>>(wa);

    const int n4 = n_nodes * D / 4;
    split_x<<<(n4 + 255) / 256, 256, 0, stream>>>((const float4*)x, (ushort4*)xh, (ushort4*)xl, n4);

    const int agg_blocks = (n_nodes * 64 + 255) / 256;
    const dim3 gemm_grid((n_nodes + 127) / 128, 2);

    // layer 0
    gemm_mfma<128, 2><<<gemm_grid, 256, 0, stream>>>(xh, xl, wl0h, wl0l, wr0h, wr0l,
                                                     b0, Pbuf, Qbuf, n_nodes);
    agg_fused128<<<agg_blocks, 256, 0, stream>>>(Pbuf, Qbuf, row_ptr, csr, inv_deg, hh, hl, n_nodes);
    // layer 1
    gemm_mfma<128, 2><<<gemm_grid, 256, 0, stream>>>(hh, hl, wl1h, wl1l, wr1h, wr1l,
                                                     b1, Pbuf, Qbuf, n_nodes);
    agg_fused128<<<agg_blocks, 256, 0, stream>>>(Pbuf, Qbuf, row_ptr, csr, inv_deg, hh, hl, n_nodes);
    // layer 2 (BN=64)
    gemm_mfma<64, 1><<<gemm_grid, 256, 0, stream>>>(hh, hl, wl2h, wl2l, wr2h, wr2l,
                                                    b2, Pbuf, Qbuf, n_nodes);
    agg64_head<<<agg_blocks, 256, 0, stream>>>(Pbuf, Qbuf, row_ptr, csr, inv_deg,
                                               wo, bo, (float*)d_out, n_nodes);
}

// Round 4
// 414.260 us; speedup vs baseline: 1.4199x; 1.1341x over previous
//
#include <hip/hip_runtime.h>
#include <hip/hip_fp16.h>

#define D 128

constexpr int SCAN_CHUNK = 1024;

using short8 = __attribute__((ext_vector_type(8))) short;
using f32x4 = __attribute__((ext_vector_type(4))) float;

// split fp32 into hi/lo bf16 (truncation; residual exact in fp32)
__device__ inline void splitf(float v, unsigned short& h, unsigned short& l) {
    unsigned b = __float_as_uint(v);
    h = (unsigned short)(b >> 16);
    float fh = __uint_as_float(b & 0xffff0000u);
    float r = v - fh;
    l = (unsigned short)(__float_as_uint(r) >> 16);
}

// ---------------- CSR build ----------------

__global__ void count_deg(const int* __restrict__ dst, int* __restrict__ deg, int n) {
    int i = blockIdx.x * blockDim.x + threadIdx.x;
    if (i < n) atomicAdd(&deg[dst[i]], 1);
}

__global__ void partial_sums(const int* __restrict__ deg, int* __restrict__ partials, int n) {
    __shared__ int sdata[256];
    int b = blockIdx.x, t = threadIdx.x;
    int base = b * SCAN_CHUNK;
    int sum = 0;
    for (int i = t; i < SCAN_CHUNK; i += 256) {
        int idx = base + i;
        if (idx < n) sum += deg[idx];
    }
    sdata[t] = sum;
    __syncthreads();
    for (int st = 128; st > 0; st >>= 1) {
        if (t < st) sdata[t] += sdata[t + st];
        __syncthreads();
    }
    if (t == 0) partials[b] = sdata[0];
}

__global__ void scan_partials(int* __restrict__ partials, int nb, int* __restrict__ total) {
    if (threadIdx.x == 0 && blockIdx.x == 0) {
        int run = 0;
        for (int i = 0; i < nb; ++i) { int v = partials[i]; partials[i] = run; run += v; }
        *total = run;
    }
}

__global__ void scan_chunks(const int* __restrict__ deg, const int* __restrict__ partials,
                            int* __restrict__ row_ptr, int* __restrict__ cursor,
                            float* __restrict__ inv_deg, int n) {
    __shared__ int soff[256];
    int b = blockIdx.x, t = threadIdx.x;
    int base = b * SCAN_CHUNK;
    int i0 = base + t * 4;
    int v[4];
    int s = 0;
#pragma unroll
    for (int j = 0; j < 4; ++j) {
        int idx = i0 + j;
        v[j] = (idx < n) ? deg[idx] : 0;
        s += v[j];
    }
    soff[t] = s;
    __syncthreads();
    for (int d = 1; d < 256; d <<= 1) {
        int val = (t >= d) ? soff[t - d] : 0;
        __syncthreads();
        soff[t] += val;
        __syncthreads();
    }
    int excl = soff[t] - s + partials[b];
#pragma unroll
    for (int j = 0; j < 4; ++j) {
        int idx = i0 + j;
        if (idx < n) {
            row_ptr[idx] = excl;
            cursor[idx] = excl;
            int dv = v[j] > 1 ? v[j] : 1;
            inv_deg[idx] = 1.0f / (float)dv;
            excl += v[j];
        }
    }
}

__global__ void fill_csr(const int* __restrict__ src, const int* __restrict__ dst,
                         int* __restrict__ cursor, int* __restrict__ csr, int n) {
    int i = blockIdx.x * blockDim.x + threadIdx.x;
    if (i < n) {
        int p = atomicAdd(&cursor[dst[i]], 1);
        csr[p] = src[i];
    }
}

// ---------------- input split: x -> xh, xl (bf16 hi/lo) ----------------
__global__ __launch_bounds__(256) void split_x(const float4* __restrict__ x,
                                               ushort4* __restrict__ xh,
                                               ushort4* __restrict__ xl, int n4) {
    int i = blockIdx.x * blockDim.x + threadIdx.x;
    if (i >= n4) return;
    float4 v = x[i];
    ushort4 h, l;
    splitf(v.x, h.x, l.x);
    splitf(v.y, h.y, l.y);
    splitf(v.z, h.z, l.z);
    splitf(v.w, h.w, l.w);
    xh[i] = h;
    xl[i] = l;
}

// ---------------- weight split+transpose: W[K=128][N] -> Wt_hi/lo [N][128] ----------------
struct WSplitArgs {
    const float* src[6];
    unsigned short* dh[6];
    unsigned short* dl[6];
    int n[6];
};

__global__ __launch_bounds__(256) void split_w(WSplitArgs a) {
    int m = blockIdx.y;
    int N = a.n[m];
    int e = blockIdx.x * 256 + threadIdx.x;
    if (e >= 128 * N) return;
    int sh = (N == 128) ? 7 : 6;
    int k = e >> sh;
    int n = e & (N - 1);
    float v = a.src[m][e];
    unsigned short h, l;
    splitf(v, h, l);
    a.dh[m][n * 128 + k] = h;
    a.dl[m][n * 128 + k] = l;
}

// ---------------- MFMA GEMM: P(fp16) = A@W1, Q(fp32) = A@W2 + bias ----------------
// A: hi/lo bf16 [M][128]. Wt: hi/lo bf16 [BN][128] (transposed).
template <int BN, int NT>
__global__ __launch_bounds__(256) void gemm_mfma(
    const unsigned short* __restrict__ Ah, const unsigned short* __restrict__ Al,
    const unsigned short* __restrict__ W1h, const unsigned short* __restrict__ W1l,
    const unsigned short* __restrict__ W2h, const unsigned short* __restrict__ W2l,
    const float* __restrict__ bias, __half* __restrict__ P, float* __restrict__ Q, int M) {
    const int tid = threadIdx.x;
    const int wave = tid >> 6;
    const int lane = tid & 63;
    const int l15 = lane & 15;
    const int q = lane >> 4;
    const int isQ = blockIdx.y;
    const unsigned short* Wh = isQ ? W2h : W1h;
    const unsigned short* Wl = isQ ? W2l : W1l;

    short8 Bh[NT][4], Bl[NT][4];
    float bvs[NT];
#pragma unroll
    for (int nt = 0; nt < NT; ++nt) {
        int n = (wave * NT + nt) * 16 + l15;
#pragma unroll
        for (int kt = 0; kt < 4; ++kt) {
            int off = n * 128 + kt * 32 + q * 8;
            Bh[nt][kt] = *(const short8*)(Wh + off);
            Bl[nt][kt] = *(const short8*)(Wl + off);
        }
        bvs[nt] = isQ ? bias[n] : 0.f;
    }

    const int m0 = blockIdx.x * 128;
    for (int mt = 0; mt < 8; ++mt) {
        int row = m0 + mt * 16 + l15;
        int rc = row < M ? row : M - 1;
        const unsigned short* ap = Ah + (size_t)rc * 128 + q * 8;
        const unsigned short* alp = Al + (size_t)rc * 128 + q * 8;
        short8 Afh[4], Afl[4];
#pragma unroll
        for (int kt = 0; kt < 4; ++kt) {
            Afh[kt] = *(const short8*)(ap + kt * 32);
            Afl[kt] = *(const short8*)(alp + kt * 32);
        }
        f32x4 acc[NT];
#pragma unroll
        for (int nt = 0; nt < NT; ++nt) acc[nt] = (f32x4)(0.f);
#pragma unroll
        for (int kt = 0; kt < 4; ++kt) {
#pragma unroll
            for (int nt = 0; nt < NT; ++nt) {
                acc[nt] = __builtin_amdgcn_mfma_f32_16x16x32_bf16(Afh[kt], Bh[nt][kt], acc[nt], 0, 0, 0);
                acc[nt] = __builtin_amdgcn_mfma_f32_16x16x32_bf16(Afh[kt], Bl[nt][kt], acc[nt], 0, 0, 0);
                acc[nt] = __builtin_amdgcn_mfma_f32_16x16x32_bf16(Afl[kt], Bh[nt][kt], acc[nt], 0, 0, 0);
            }
        }
        int orow = m0 + mt * 16 + q * 4;
#pragma unroll
        for (int nt = 0; nt < NT; ++nt) {
            int col = (wave * NT + nt) * 16 + l15;
#pragma unroll
            for (int r = 0; r < 4; ++r) {
                int rr = orow + r;
                if (rr < M) {
                    if (isQ) Q[(size_t)rr * BN + col] = acc[nt][r] + bvs[nt];
                    else P[(size_t)rr * BN + col] = __float2half(acc[nt][r]);
                }
            }
        }
    }
}

// ---------------- fused aggregation 128-dim, fp16 gather ----------------
// 2 edges per wave-instruction: lanes 0-31 -> even slot, 32-63 -> odd slot.
// lane covers cols 4*(lane&31) .. +3 via half4 (8B). x4 unroll -> 8 edges in flight.
__global__ __launch_bounds__(256) void agg_fused128(
    const __half* __restrict__ P, const float* __restrict__ Q,
    const int* __restrict__ row_ptr, const int* __restrict__ csr,
    const float* __restrict__ inv_deg, unsigned short* __restrict__ Hh,
    unsigned short* __restrict__ Hl, int n_nodes) {
    int node = (blockIdx.x * blockDim.x + threadIdx.x) >> 6;
    int lane = threadIdx.x & 63;
    if (node >= n_nodes) return;
    int beg = row_ptr[node], end = row_ptr[node + 1];
    const int half = lane >> 5;
    const int l = lane & 31;
    float a[4][4] = {};
    int e = beg;
    for (; e + 8 <= end; e += 8) {
#pragma unroll
        for (int j = 0; j < 4; ++j) {
            int s = csr[e + 2 * j + half];
            uint2 raw = *(const uint2*)(P + (size_t)s * 128 + l * 4);
            float2 f01 = __half22float2(*reinterpret_cast<__half2*>(&raw.x));
            float2 f23 = __half22float2(*reinterpret_cast<__half2*>(&raw.y));
            a[j][0] += f01.x; a[j][1] += f01.y; a[j][2] += f23.x; a[j][3] += f23.y;
        }
    }
    for (; e < end; e += 2) {
        int idx = e + half;
        if (idx < end) {
            int s = csr[idx];
            uint2 raw = *(const uint2*)(P + (size_t)s * 128 + l * 4);
            float2 f01 = __half22float2(*reinterpret_cast<__half2*>(&raw.x));
            float2 f23 = __half22float2(*reinterpret_cast<__half2*>(&raw.y));
            a[0][0] += f01.x; a[0][1] += f01.y; a[0][2] += f23.x; a[0][3] += f23.y;
        }
    }
    float s0 = (a[0][0] + a[1][0]) + (a[2][0] + a[3][0]);
    float s1 = (a[0][1] + a[1][1]) + (a[2][1] + a[3][1]);
    float s2 = (a[0][2] + a[1][2]) + (a[2][2] + a[3][2]);
    float s3 = (a[0][3] + a[1][3]) + (a[2][3] + a[3][3]);
    s0 += __shfl_xor(s0, 32);
    s1 += __shfl_xor(s1, 32);
    s2 += __shfl_xor(s2, 32);
    s3 += __shfl_xor(s3, 32);
    if (lane < 32) {
        float w = inv_deg[node];
        float4 qv = ((const float4*)Q)[(size_t)node * 32 + l];
        float h0 = fmaxf(fmaf(s0, w, qv.x), 0.f);
        float h1 = fmaxf(fmaf(s1, w, qv.y), 0.f);
        float h2 = fmaxf(fmaf(s2, w, qv.z), 0.f);
        float h3 = fmaxf(fmaf(s3, w, qv.w), 0.f);
        ushort4 hv, lv;
        splitf(h0, hv.x, lv.x);
        splitf(h1, hv.y, lv.y);
        splitf(h2, hv.z, lv.z);
        splitf(h3, hv.w, lv.w);
        ((ushort4*)Hh)[(size_t)node * 32 + l] = hv;
        ((ushort4*)Hl)[(size_t)node * 32 + l] = lv;
    }
}

// ---------------- fused aggregation 64-dim (fp16 gather) + output head ----------------
// 4 edges per wave-instruction: quarter = lane>>4 picks edge slot; 16 lanes x half4 = 128B/edge.
__global__ __launch_bounds__(256) void agg64_head(
    const __half* __restrict__ P, const float* __restrict__ Q,
    const int* __restrict__ row_ptr, const int* __restrict__ csr,
    const float* __restrict__ inv_deg, const float* __restrict__ Wo,
    const float* __restrict__ bo, float* __restrict__ out, int n_nodes) {
    int node = (blockIdx.x * blockDim.x + threadIdx.x) >> 6;
    int lane = threadIdx.x & 63;
    if (node >= n_nodes) return;
    int beg = row_ptr[node], end = row_ptr[node + 1];
    const int quarter = lane >> 4;
    const int l = lane & 15;
    float a[2][4] = {};
    int e = beg;
    for (; e + 8 <= end; e += 8) {
#pragma unroll
        for (int j = 0; j < 2; ++j) {
            int s = csr[e + 4 * j + quarter];
            uint2 raw = *(const uint2*)(P + (size_t)s * 64 + l * 4);
            float2 f01 = __half22float2(*reinterpret_cast<__half2*>(&raw.x));
            float2 f23 = __half22float2(*reinterpret_cast<__half2*>(&raw.y));
            a[j][0] += f01.x; a[j][1] += f01.y; a[j][2] += f23.x; a[j][3] += f23.y;
        }
    }
    for (; e < end; e += 4) {
        int idx = e + quarter;
        if (idx < end) {
            int s = csr[idx];
            uint2 raw = *(const uint2*)(P + (size_t)s * 64 + l * 4);
            float2 f01 = __half22float2(*reinterpret_cast<__half2*>(&raw.x));
            float2 f23 = __half22float2(*reinterpret_cast<__half2*>(&raw.y));
            a[0][0] += f01.x; a[0][1] += f01.y; a[0][2] += f23.x; a[0][3] += f23.y;
        }
    }
    float s0 = a[0][0] + a[1][0];
    float s1 = a[0][1] + a[1][1];
    float s2 = a[0][2] + a[1][2];
    float s3 = a[0][3] + a[1][3];
    s0 += __shfl_xor(s0, 16); s0 += __shfl_xor(s0, 32);
    s1 += __shfl_xor(s1, 16); s1 += __shfl_xor(s1, 32);
    s2 += __shfl_xor(s2, 16); s2 += __shfl_xor(s2, 32);
    s3 += __shfl_xor(s3, 16); s3 += __shfl_xor(s3, 32);
    if (lane < 16) {
        float w = inv_deg[node];
        float4 qv = ((const float4*)Q)[(size_t)node * 16 + l];
        float h0 = fmaxf(fmaf(s0, w, qv.x), 0.f);
        float h1 = fmaxf(fmaf(s1, w, qv.y), 0.f);
        float h2 = fmaxf(fmaf(s2, w, qv.z), 0.f);
        float h3 = fmaxf(fmaf(s3, w, qv.w), 0.f);
        const float4* Wo4 = (const float4*)Wo;
        float4 w0 = Wo4[4 * l + 0], w1 = Wo4[4 * l + 1], w2 = Wo4[4 * l + 2], w3 = Wo4[4 * l + 3];
        float c0 = h0 * w0.x + h1 * w1.x + h2 * w2.x + h3 * w3.x;
        float c1 = h0 * w0.y + h1 * w1.y + h2 * w2.y + h3 * w3.y;
        float c2 = h0 * w0.z + h1 * w1.z + h2 * w2.z + h3 * w3.z;
        float c3 = h0 * w0.w + h1 * w1.w + h2 * w2.w + h3 * w3.w;
#pragma unroll
        for (int m = 8; m > 0; m >>= 1) {
            c0 += __shfl_xor(c0, m);
            c1 += __shfl_xor(c1, m);
            c2 += __shfl_xor(c2, m);
            c3 += __shfl_xor(c3, m);
        }
        if (l == 0) {
            float4 r;
            r.x = c0 + bo[0];
            r.y = c1 + bo[1];
            r.z = c2 + bo[2];
            r.w = c3 + bo[3];
            ((float4*)out)[node] = r;
        }
    }
}

extern "C" void kernel_launch(void* const* d_in, const int* in_sizes, int n_in,
                              void* d_out, int out_size, void* d_ws, size_t ws_size,
                              hipStream_t stream) {
    const float* x = (const float*)d_in[0];
    const int* ei = (const int*)d_in[1];
    const float* wl0 = (const float*)d_in[3];
    const float* wr0 = (const float*)d_in[4];
    const float* b0 = (const float*)d_in[5];
    const float* wl1 = (const float*)d_in[6];
    const float* wr1 = (const float*)d_in[7];
    const float* b1 = (const float*)d_in[8];
    const float* wl2 = (const float*)d_in[9];
    const float* wr2 = (const float*)d_in[10];
    const float* b2 = (const float*)d_in[11];
    const float* wo = (const float*)d_in[12];
    const float* bo = (const float*)d_in[13];

    const int n_nodes = in_sizes[0] / D;   // 50000
    const int n_edges = in_sizes[1] / 2;   // 800000
    const int* srcp = ei;
    const int* dstp = ei + n_edges;

    char* ws = (char*)d_ws;
    size_t off = 0;
    auto carve = [&](size_t bytes) -> void* {
        void* p = ws + off;
        off = (off + bytes + 255) & ~(size_t)255;
        return p;
    };
    int* deg = (int*)carve((size_t)n_nodes * 4);
    int* row_ptr = (int*)carve((size_t)(n_nodes + 1) * 4);
    int* cursor = (int*)carve((size_t)n_nodes * 4);
    int* partials = (int*)carve(256 * 4);
    float* inv_deg = (float*)carve((size_t)n_nodes * 4);
    int* csr = (int*)carve((size_t)n_edges * 4);
    unsigned short* xh = (unsigned short*)carve((size_t)n_nodes * D * 2);
    unsigned short* xl = (unsigned short*)carve((size_t)n_nodes * D * 2);
    __half* Pbuf = (__half*)carve((size_t)n_nodes * D * 2);
    float* Qbuf = (float*)carve((size_t)n_nodes * D * 4);
    unsigned short* hh = (unsigned short*)carve((size_t)n_nodes * D * 2);
    unsigned short* hl = (unsigned short*)carve((size_t)n_nodes * D * 2);
    unsigned short* wt = (unsigned short*)carve((size_t)(4 * 128 * 128 + 2 * 64 * 128) * 2 * 2);
    unsigned short* wl0h = wt;
    unsigned short* wl0l = wl0h + 128 * 128;
    unsigned short* wr0h = wl0l + 128 * 128;
    unsigned short* wr0l = wr0h + 128 * 128;
    unsigned short* wl1h = wr0l + 128 * 128;
    unsigned short* wl1l = wl1h + 128 * 128;
    unsigned short* wr1h = wl1l + 128 * 128;
    unsigned short* wr1l = wr1h + 128 * 128;
    unsigned short* wl2h = wr1l + 128 * 128;
    unsigned short* wl2l = wl2h + 64 * 128;
    unsigned short* wr2h = wl2l + 64 * 128;
    unsigned short* wr2l = wr2h + 64 * 128;

    const int nchunk = (n_nodes + SCAN_CHUNK - 1) / SCAN_CHUNK;

    hipMemsetAsync(deg, 0, (size_t)n_nodes * 4, stream);
    count_deg<<<(n_edges + 255) / 256, 256, 0, stream>>>(dstp, deg, n_edges);
    partial_sums<<<nchunk, 256, 0, stream>>>(deg, partials, n_nodes);
    scan_partials<<<1, 64, 0, stream>>>(partials, nchunk, row_ptr + n_nodes);
    scan_chunks<<<nchunk, 256, 0, stream>>>(deg, partials, row_ptr, cursor, inv_deg, n_nodes);
    fill_csr<<<(n_edges + 255) / 256, 256, 0, stream>>>(srcp, dstp, cursor, csr, n_edges);

    WSplitArgs wa;
    wa.src[0] = wl0; wa.dh[0] = wl0h; wa.dl[0] = wl0l; wa.n[0] = 128;
    wa.src[1] = wr0; wa.dh[1] = wr0h; wa.dl[1] = wr0l; wa.n[1] = 128;
    wa.src[2] = wl1; wa.dh[2] = wl1h; wa.dl[2] = wl1l; wa.n[2] = 128;
    wa.src[3] = wr1; wa.dh[3] = wr1h; wa.dl[3] = wr1l; wa.n[3] = 128;
    wa.src[4] = wl2; wa.dh[4] = wl2h; wa.dl[4] = wl2l; wa.n[4] = 64;
    wa.src[5] = wr2; wa.dh[5] = wr2h; wa.dl[5] = wr2l; wa.n[5] = 64;
    split_w<<<dim3(64, 6), 256, 0, stream>>>(wa);

    const int n4 = n_nodes * D / 4;
    split_x<<<(n4 + 255) / 256, 256, 0, stream>>>((const float4*)x, (ushort4*)xh, (ushort4*)xl, n4);

    const int agg_blocks = (n_nodes * 64 + 255) / 256;
    const dim3 gemm_grid((n_nodes + 127) / 128, 2);

    // layer 0
    gemm_mfma<128, 2><<<gemm_grid, 256, 0, stream>>>(xh, xl, wl0h, wl0l, wr0h, wr0l,
                                                     b0, Pbuf, Qbuf, n_nodes);
    agg_fused128<<<agg_blocks, 256, 0, stream>>>(Pbuf, Qbuf, row_ptr, csr, inv_deg, hh, hl, n_nodes);
    // layer 1
    gemm_mfma<128, 2><<<gemm_grid, 256, 0, stream>>>(hh, hl, wl1h, wl1l, wr1h, wr1l,
                                                     b1, Pbuf, Qbuf, n_nodes);
    agg_fused128<<<agg_blocks, 256, 0, stream>>>(Pbuf, Qbuf, row_ptr, csr, inv_deg, hh, hl, n_nodes);
    // layer 2 (BN=64)
    gemm_mfma<64, 1><<<gemm_grid, 256, 0, stream>>>(hh, hl, wl2h, wl2l, wr2h, wr2l,
                                                    b2, Pbuf, Qbuf, n_nodes);
    agg64_head<<<agg_blocks, 256, 0, stream>>>(Pbuf, Qbuf, row_ptr, csr, inv_deg,
                                               wo, bo, (float*)d_out, n_nodes);
}